// Round 3
// baseline (615.103 us; speedup 1.0000x reference)
//
#include <hip/hip_runtime.h>
#include <math.h>

typedef unsigned short u16;
typedef unsigned int   u32;
typedef short bf16x8 __attribute__((ext_vector_type(8)));
typedef float f32x4  __attribute__((ext_vector_type(4)));

// ---------- helpers ----------
__device__ __forceinline__ u16 f2bf(float f) {          // RNE fp32 -> bf16 (prep only)
  u32 u = __builtin_bit_cast(u32, f);
  u32 r = (u + 0x7fffu + ((u >> 16) & 1u)) >> 16;
  return (u16)r;
}
__device__ __forceinline__ u32 pkbf(float lo, float hi) {  // packed RNE pair
  u32 r;
  asm("v_cvt_pk_bf16_f32 %0, %1, %2" : "=v"(r) : "v"(lo), "v"(hi));
  return r;
}
// branch-free exact-enough gelu: erf via A&S 7.1.26 (|err| <= 1.5e-7)
__device__ __forceinline__ float gelu_fast(float v) {
  const float xa = fabsf(v) * 0.70710678118654752f;
  const float t  = __builtin_amdgcn_rcpf(fmaf(0.3275911f, xa, 1.0f));
  float p = fmaf(1.061405429f, t, -1.453152027f);
  p = fmaf(p, t, 1.421413741f);
  p = fmaf(p, t, -0.284496736f);
  p = fmaf(p, t, 0.254829592f);
  p = p * t;
  const float e  = __expf(-xa * xa);
  const float g  = 0.5f * v * (p * e);      // 0.5*v*(1-erf(|x|))
  return (v >= 0.f) ? (v - g) : g;
}

// ws layout (bytes): [h bf16 channels-last [b][h][w][200]: 209715200][fw1][fw2]
#define H_BYTES   209715200ll
#define FW1_ELEMS 26624   // 4 kc * 13 nt * 64 lanes * 8
#define FW2_ELEMS 25088   // 7 kc * 7 nt * 64 lanes * 8

// ---------- weight fragment pre-swizzle (UNCHANGED) ----------
// frag element j of lane, tile (kc,nt):  W[o = nt*16 + (lane&15)][c = kc*32 + (lane>>4)*8 + j]
__global__ void prep_frags(const float* __restrict__ w1, const float* __restrict__ w2,
                           u16* __restrict__ fw1, u16* __restrict__ fw2) {
  int gid = blockIdx.x * 256 + threadIdx.x;
  if (gid < FW1_ELEMS) {
    int j = gid & 7, lane = (gid >> 3) & 63, rest = gid >> 9;   // rest = kc*13+nt
    int nt = rest % 13, kc = rest / 13;
    int c = kc * 32 + (lane >> 4) * 8 + j;
    int o = nt * 16 + (lane & 15);
    float v = (c < 100 && o < 200) ? w1[o * 100 + c] : 0.f;
    fw1[gid] = f2bf(v);
  } else if (gid < FW1_ELEMS + FW2_ELEMS) {
    int i2 = gid - FW1_ELEMS;
    int j = i2 & 7, lane = (i2 >> 3) & 63, rest = i2 >> 9;      // rest = kc*7+nt
    int nt = rest % 7, kc = rest / 7;
    int c = kc * 32 + (lane >> 4) * 8 + j;
    int o = nt * 16 + (lane & 15);
    float v = (c < 200 && o < 100) ? w2[o * 200 + c] : 0.f;
    fw2[i2] = f2bf(v);
  }
}

// per-element shifted-x gather (exec-masked load, zero outside)
__device__ __forceinline__ float loadx(const float* __restrict__ x,
                                       int b, int hh, int wp, int c) {
  float v = 0.f;
  if (c < 100) {
    const int dw = (c < 20) ? 1 : ((c < 40) ? -1 : 0);
    const int dh = (c >= 40 && c < 60) ? 1 : ((c >= 60 && c < 80) ? -1 : 0);
    const int hs = hh + dh, ws = wp + dw;
    if ((unsigned)hs < 256u && (unsigned)ws < 256u)
      v = x[((b * 100 + c) * 256 + hs) * 256 + ws];
  }
  return v;
}

// ---------- conv1: h = gelu(shift5(x) @ w1^T + b1), bf16 channels-last ----------
// zero LDS, zero barriers: A-frags direct to registers, D direct to global.
__global__ __launch_bounds__(256, 4) void conv1_kernel(
    const float* __restrict__ x, const u16* __restrict__ fw1,
    const float* __restrict__ b1, u16* __restrict__ hbuf) {
  const int t   = threadIdx.x;
  const int bid = blockIdx.x;
  const int bx  = ((bid & 7) << 10) | (bid >> 3);  // XCD k owns batch k (bijective)
  const int b  = bx >> 10;
  const int hh = (bx >> 2) & 255;
  const int w0 = (bx & 3) << 6;                    // 64-px quarter row

  const int lane = t & 63, wid = t >> 6;
  const int col = lane & 15, q = lane >> 4;
  const int px = w0 + wid * 16 + col;              // this lane's w coordinate

  // ---- A-fragments: 32 scalar dword loads -> 4x bf16x8 in registers ----
  uint4 aw[4];
  #pragma unroll
  for (int kc = 0; kc < 4; ++kc) {
    u32 wd[4];
    #pragma unroll
    for (int p = 0; p < 4; ++p) {
      const int c0 = kc * 32 + q * 8 + 2 * p;
      const float v0 = loadx(x, b, hh, px, c0);
      const float v1 = loadx(x, b, hh, px, c0 + 1);
      wd[p] = pkbf(v0, v1);
    }
    aw[kc] = make_uint4(wd[0], wd[1], wd[2], wd[3]);
  }

  // ---- K loop: swapped operands -> lane holds px=col, o rows ----
  f32x4 acc[13];
  #pragma unroll
  for (int nt = 0; nt < 13; ++nt) acc[nt] = (f32x4)0.0f;

  const bf16x8* wf = (const bf16x8*)fw1 + lane;
  #pragma unroll
  for (int kc = 0; kc < 4; ++kc) {
    const bf16x8 a = __builtin_bit_cast(bf16x8, aw[kc]);
    #pragma unroll
    for (int nt = 0; nt < 13; ++nt) {
      const bf16x8 bf = wf[(kc * 13 + nt) * 64];
      acc[nt] = __builtin_amdgcn_mfma_f32_16x16x32_bf16(bf, a, acc[nt], 0, 0, 0);
    }
  }

  // ---- epilogue: bias + gelu + pack, direct 8B stores (lines merge in L2) ----
  const int rowu = ((b * 256 + hh) * 256 + px) * 200;     // u16 index of this px row
  #pragma unroll
  for (int nt = 0; nt < 13; ++nt) {
    const int ob = nt * 16 + 4 * q;                       // multiple of 4
    if (ob < 200) {
      const float4 b4 = *(const float4*)&b1[ob];
      const f32x4 v = acc[nt];
      const u32 p0 = pkbf(gelu_fast(v[0] + b4.x), gelu_fast(v[1] + b4.y));
      const u32 p1 = pkbf(gelu_fast(v[2] + b4.z), gelu_fast(v[3] + b4.w));
      *(uint2*)&hbuf[rowu + ob] = make_uint2(p0, p1);
    }
  }
}

// ---------- conv2: out = shift5(h) @ w2^T + b2 (fp32, channels-first out) ----------
// A-frags direct to registers (channels-last h: 1 uint4 per frag); Ob LDS transpose kept.
#define PS2 68    // Ob px-stride (f32): 64 + 4
__global__ __launch_bounds__(256, 4) void conv2_kernel(
    const u16* __restrict__ hbuf, const u16* __restrict__ fw2,
    const float* __restrict__ b2, float* __restrict__ out) {
  __shared__ __align__(16) float Ob[112 * PS2];           // 30464 B
  const int t   = threadIdx.x;
  const int bid = blockIdx.x;
  const int bx  = ((bid & 7) << 10) | (bid >> 3);
  const int b  = bx >> 10;
  const int hh = (bx >> 2) & 255;
  const int w0 = (bx & 3) << 6;

  const int lane = t & 63, wid = t >> 6;
  const int col = lane & 15, q = lane >> 4;
  const int px = w0 + wid * 16 + col;

  // ---- A-fragments: 7 independent uint4 loads, shift uniform per 8-pack ----
  uint4 aw[7];
  #pragma unroll
  for (int kc = 0; kc < 7; ++kc) {
    const int c0 = kc * 32 + q * 8;
    uint4 d = make_uint4(0u, 0u, 0u, 0u);
    if (c0 < 200) {                                       // 200/208/216: K-pad
      const int dw = (c0 < 40) ? 1 : ((c0 < 80) ? -1 : 0);
      const int dh = (c0 >= 80 && c0 < 120) ? 1 : ((c0 >= 120 && c0 < 160) ? -1 : 0);
      const int hs = hh + dh, ws = px + dw;
      const bool ok = ((unsigned)hs < 256u) && ((unsigned)ws < 256u);
      const int hsc = ok ? hs : hh;                       // clamped, unconditional load
      const int wsc = ok ? ws : px;
      d = *(const uint4*)&hbuf[((b * 256 + hsc) * 256 + wsc) * 200 + c0];
      if (!ok) d = make_uint4(0u, 0u, 0u, 0u);
    }
    aw[kc] = d;
  }

  // ---- K loop: lane holds o=col, px rows ----
  f32x4 acc[7];
  #pragma unroll
  for (int nt = 0; nt < 7; ++nt) acc[nt] = (f32x4)0.0f;

  const bf16x8* wf = (const bf16x8*)fw2 + lane;
  #pragma unroll
  for (int kc = 0; kc < 7; ++kc) {
    const bf16x8 a = __builtin_bit_cast(bf16x8, aw[kc]);
    #pragma unroll
    for (int nt = 0; nt < 7; ++nt) {
      const bf16x8 bf = wf[(kc * 7 + nt) * 64];
      acc[nt] = __builtin_amdgcn_mfma_f32_16x16x32_bf16(a, bf, acc[nt], 0, 0, 0);
    }
  }

  // ---- epilogue: + b2 into [o][px] fp32 tile, then coalesced stores ----
  #pragma unroll
  for (int nt = 0; nt < 7; ++nt) {
    const int o = nt * 16 + col;
    const float bias = (o < 100) ? b2[o] : 0.f;
    const f32x4 v = acc[nt];
    *(float4*)&Ob[o * PS2 + wid * 16 + 4 * q] =
        make_float4(v[0] + bias, v[1] + bias, v[2] + bias, v[3] + bias);
  }
  __syncthreads();
  {
    const int obase = b * 6553600 + hh * 256 + w0;   // (b*100+oo)*65536 + hh*256 + w0
    #pragma unroll
    for (int s = 0; s < 7; ++s) {
      const int id = s * 256 + t;                    // 100 oo * 16 chunks = 1600
      if (id < 1600) {
        const int oo = id >> 4, ch = id & 15;
        const float4 d = *(const float4*)&Ob[oo * PS2 + ch * 4];
        *(float4*)&out[obase + oo * 65536 + ch * 4] = d;
      }
    }
  }
}

extern "C" void kernel_launch(void* const* d_in, const int* in_sizes, int n_in,
                              void* d_out, int out_size, void* d_ws, size_t ws_size,
                              hipStream_t stream) {
  const float* x  = (const float*)d_in[0];
  const float* w1 = (const float*)d_in[1];
  const float* b1 = (const float*)d_in[2];
  const float* w2 = (const float*)d_in[3];
  const float* b2 = (const float*)d_in[4];
  float* out = (float*)d_out;

  u16* hbuf = (u16*)d_ws;
  u16* fw1  = (u16*)((char*)d_ws + H_BYTES);
  u16* fw2  = (u16*)((char*)d_ws + H_BYTES + FW1_ELEMS * 2);

  prep_frags<<<202, 256, 0, stream>>>(w1, w2, fw1, fw2);
  conv1_kernel<<<8192, 256, 0, stream>>>(x, fw1, b1, hbuf);
  conv2_kernel<<<8192, 256, 0, stream>>>(hbuf, fw2, b2, out);
}